// Round 1
// baseline (1157.938 us; speedup 1.0000x reference)
//
#include <hip/hip_runtime.h>
#include <hip/hip_bf16.h>

#define S_N 100000
#define E_N 30000
#define K_N 1000
#define D_K 64
#define F_K 128
#define B_N 16384
#define NNZ_S 1600000
#define NNZ_E 480000
#define NNZ_K 32000
#define NNZ_TOT (NNZ_S + NNZ_E + NNZ_K)

// scan chunking: 2048 elements per block (256 threads x 8)
#define CH_S 49   // ceil(100000/2048)
#define CH_E 15   // ceil(30000/2048)
#define CH_K 1
#define CH_TOT (CH_S + CH_E + CH_K)

typedef __attribute__((ext_vector_type(8))) short sh8;
typedef __attribute__((ext_vector_type(4))) float f4;

// ---------------------------------------------------------------- CSR build
__global__ void count_kernel(const int* __restrict__ sr, const int* __restrict__ er,
                             const int* __restrict__ kr,
                             int* cnt_s, int* cnt_e, int* cnt_k) {
    int i = blockIdx.x * 256 + threadIdx.x;
    if (i >= NNZ_TOT) return;
    if (i < NNZ_S) atomicAdd(&cnt_s[sr[i]], 1);
    else if (i < NNZ_S + NNZ_E) atomicAdd(&cnt_e[er[i - NNZ_S]], 1);
    else atomicAdd(&cnt_k[kr[i - NNZ_S - NNZ_E]], 1);
}

__device__ inline void seg_map(int b, const int* cnt_s, const int* cnt_e, const int* cnt_k,
                               const int** src, int* len, int* chunk, int* seg) {
    if (b < CH_S)            { *src = cnt_s; *len = S_N; *chunk = b;            *seg = 0; }
    else if (b < CH_S + CH_E){ *src = cnt_e; *len = E_N; *chunk = b - CH_S;     *seg = 1; }
    else                     { *src = cnt_k; *len = K_N; *chunk = 0;            *seg = 2; }
}

__global__ void scan_a(const int* cnt_s, const int* cnt_e, const int* cnt_k, int* partials) {
    const int* src; int len, chunk, seg;
    seg_map(blockIdx.x, cnt_s, cnt_e, cnt_k, &src, &len, &chunk, &seg);
    int base = chunk * 2048 + threadIdx.x * 8;
    int s = 0;
    for (int j = 0; j < 8; j++) { int idx = base + j; if (idx < len) s += src[idx]; }
    __shared__ int red[256];
    red[threadIdx.x] = s; __syncthreads();
    for (int off = 128; off > 0; off >>= 1) {
        if (threadIdx.x < off) red[threadIdx.x] += red[threadIdx.x + off];
        __syncthreads();
    }
    if (threadIdx.x == 0) partials[blockIdx.x] = red[0];
}

__global__ void scan_b(const int* partials, int* chunk_off, int* rp_s, int* rp_e, int* rp_k) {
    if (threadIdx.x == 0 && blockIdx.x == 0) {
        int acc = 0;
        for (int i = 0; i < CH_S; i++) { chunk_off[i] = acc; acc += partials[i]; }
        rp_s[S_N] = acc;
        acc = 0;
        for (int i = CH_S; i < CH_S + CH_E; i++) { chunk_off[i] = acc; acc += partials[i]; }
        rp_e[E_N] = acc;
        chunk_off[CH_S + CH_E] = 0;
        rp_k[K_N] = partials[CH_S + CH_E];
    }
}

__global__ void scan_c(const int* cnt_s, const int* cnt_e, const int* cnt_k,
                       const int* chunk_off,
                       int* rp_s, int* rp_e, int* rp_k,
                       int* nx_s, int* nx_e, int* nx_k) {
    const int* src; int len, chunk, seg;
    seg_map(blockIdx.x, cnt_s, cnt_e, cnt_k, &src, &len, &chunk, &seg);
    int* rp = (seg == 0) ? rp_s : (seg == 1) ? rp_e : rp_k;
    int* nx = (seg == 0) ? nx_s : (seg == 1) ? nx_e : nx_k;
    int t = threadIdx.x;
    int base = chunk * 2048 + t * 8;
    int v[8]; int s = 0;
    for (int j = 0; j < 8; j++) { int idx = base + j; v[j] = (idx < len) ? src[idx] : 0; s += v[j]; }
    __shared__ int sd[256];
    sd[t] = s; __syncthreads();
    for (int off = 1; off < 256; off <<= 1) {
        int x = (t >= off) ? sd[t - off] : 0;
        __syncthreads();
        sd[t] += x;
        __syncthreads();
    }
    int pre = sd[t] - s + chunk_off[blockIdx.x];
    for (int j = 0; j < 8; j++) {
        int idx = base + j;
        if (idx < len) { rp[idx] = pre; nx[idx] = pre; pre += v[j]; }
    }
}

__global__ void scatter_kernel(const int* sr, const int* sc, const float* sv,
                               const int* er, const int* ec, const float* ev,
                               const int* kr, const int* kc, const float* kv,
                               int* nx_s, int* nx_e, int* nx_k,
                               int* cs_s, float* vs_s, int* cs_e, float* vs_e,
                               int* cs_k, float* vs_k) {
    int i = blockIdx.x * 256 + threadIdx.x;
    if (i >= NNZ_TOT) return;
    if (i < NNZ_S) {
        int r = sr[i]; int p = atomicAdd(&nx_s[r], 1);
        cs_s[p] = sc[i]; vs_s[p] = sv[i];
    } else if (i < NNZ_S + NNZ_E) {
        int ii = i - NNZ_S;
        int r = er[ii]; int p = atomicAdd(&nx_e[r], 1);
        cs_e[p] = ec[ii]; vs_e[p] = ev[ii];
    } else {
        int ii = i - NNZ_S - NNZ_E;
        int r = kr[ii]; int p = atomicAdd(&nx_k[r], 1);
        cs_k[p] = kc[ii]; vs_k[p] = kv[ii];
    }
}

// --------------------------------------------------------- convolution SpMM
// one wave per row, lane = feature d; y[r] = 0.9*x[r] + sum val*x[col]
__global__ void spmm3(const int* __restrict__ rp_s, const int* __restrict__ cs_s,
                      const float* __restrict__ vs_s, const float* __restrict__ xs, float* ys,
                      const int* __restrict__ rp_e, const int* __restrict__ cs_e,
                      const float* __restrict__ vs_e, const float* __restrict__ xe, float* ye,
                      const int* __restrict__ rp_k, const int* __restrict__ cs_k,
                      const float* __restrict__ vs_k, const float* __restrict__ xk, float* yk) {
    int w = (blockIdx.x * 256 + threadIdx.x) >> 6;
    int d = threadIdx.x & 63;
    const int* rp; const int* cs; const float* vs; const float* x; float* y; int r;
    if (w < S_N) { rp = rp_s; cs = cs_s; vs = vs_s; x = xs; y = ys; r = w; }
    else if (w < S_N + E_N) { rp = rp_e; cs = cs_e; vs = vs_e; x = xe; y = ye; r = w - S_N; }
    else if (w < S_N + E_N + K_N) { rp = rp_k; cs = cs_k; vs = vs_k; x = xk; y = yk; r = w - S_N - E_N; }
    else return;
    int j0 = rp[r], j1 = rp[r + 1];
    float acc = 0.9f * x[(long)r * 64 + d];
    for (int j = j0; j < j1; j++) {
        int c = cs[j]; float v = vs[j];
        acc += v * x[(long)c * 64 + d];
    }
    y[(long)r * 64 + d] = acc;
}

// ------------------------------------------------- batch accumulator gathers
// bacc_s[b] (+)= src_s[sid[b]]; bacc_e[b] (+)= src_e[eid[b]]; kacc (+)= src_k
__global__ void gather_acc(const int* __restrict__ sid, const int* __restrict__ eid,
                           const float* __restrict__ src_s, const float* __restrict__ src_e,
                           const float* __restrict__ src_k,
                           float* bacc_s, float* bacc_e, float* kacc, int init) {
    int i = blockIdx.x * 256 + threadIdx.x;
    const int BD = B_N * 64;
    if (i < BD) {
        int b = i >> 6, d = i & 63;
        float v = src_s[(long)sid[b] * 64 + d];
        bacc_s[i] = init ? v : bacc_s[i] + v;
    } else if (i < 2 * BD) {
        int ii = i - BD; int b = ii >> 6, d = ii & 63;
        float v = src_e[(long)eid[b] * 64 + d];
        bacc_e[ii] = init ? v : bacc_e[ii] + v;
    } else if (i < 2 * BD + K_N * 64) {
        int ii = i - 2 * BD;
        float v = src_k[ii];
        kacc[ii] = init ? v : kacc[ii] + v;
    }
}

// --------------------------------------------- small dense layers (D=64 -> F=128)
// block: 2 rows x 128 cols; X = 0.25*(bacc + cur3[id]); out = leaky(X@W + b) in bf16
__global__ void dense_mm(const int* __restrict__ sid, const int* __restrict__ eid,
                         const float* __restrict__ bacc_s, const float* __restrict__ cur3_s,
                         const float* __restrict__ bacc_e, const float* __restrict__ cur3_e,
                         const float* __restrict__ W_stu, const float* __restrict__ b_stu,
                         const float* __restrict__ W_exer, const float* __restrict__ b_exer,
                         __hip_bfloat16* st_b, __hip_bfloat16* df_b) {
    int which = blockIdx.y;
    const int* id = which ? eid : sid;
    const float* bacc = which ? bacc_e : bacc_s;
    const float* cur3 = which ? cur3_e : cur3_s;
    const float* W = which ? W_exer : W_stu;
    const float* bias = which ? b_exer : b_stu;
    __hip_bfloat16* out = which ? df_b : st_b;
    int r0 = blockIdx.x * 2;
    int t = threadIdx.x;
    __shared__ float X[2][64];
    if (t < 128) {
        int lr = t >> 6, d = t & 63; int b = r0 + lr;
        X[lr][d] = 0.25f * (bacc[(long)b * 64 + d] + cur3[(long)id[b] * 64 + d]);
    }
    __syncthreads();
    int lr = t >> 7, f = t & 127;
    float acc = bias[f];
    for (int d = 0; d < 64; d++) acc += X[lr][d] * W[d * 128 + f];
    acc = acc > 0.f ? acc : 0.1f * acc;
    out[(long)(r0 + lr) * 128 + f] = __float2bfloat16(acc);
}

// knowledge: rows padded to 1024; writes f32 to d_out and bf16 (zero-padded) to ws
__global__ void know_mm(const float* __restrict__ kacc, const float* __restrict__ cur3_k,
                        const float* __restrict__ W, const float* __restrict__ bias,
                        float* out_f32, __hip_bfloat16* kn_b) {
    int r0 = blockIdx.x * 2;
    int t = threadIdx.x;
    __shared__ float X[2][64];
    if (t < 128) {
        int lr = t >> 6, d = t & 63; int r = r0 + lr;
        X[lr][d] = (r < K_N) ? 0.25f * (kacc[r * 64 + d] + cur3_k[r * 64 + d]) : 0.f;
    }
    __syncthreads();
    int lr = t >> 7, f = t & 127; int r = r0 + lr;
    float acc = bias[f];
    for (int d = 0; d < 64; d++) acc += X[lr][d] * W[d * 128 + f];
    acc = acc > 0.f ? acc : 0.1f * acc;
    if (r < K_N) {
        out_f32[(long)r * 128 + f] = acc;
        kn_b[(long)r * 128 + f] = __float2bfloat16(acc);
    } else {
        kn_b[(long)r * 128 + f] = __float2bfloat16(0.f);
    }
}

// disc = sigmoid(0.25*(bacc_e+cur3_e[eid]) . W_disc + b_disc), one wave per row
__global__ void disc_kernel(const int* __restrict__ eid,
                            const float* __restrict__ bacc_e, const float* __restrict__ cur3_e,
                            const float* __restrict__ W_disc, const float* __restrict__ b_disc,
                            float* out) {
    int w = (blockIdx.x * 256 + threadIdx.x) >> 6;
    int d = threadIdx.x & 63;
    if (w >= B_N) return;
    float x = 0.25f * (bacc_e[(long)w * 64 + d] + cur3_e[(long)eid[w] * 64 + d]) * W_disc[d];
    for (int off = 32; off > 0; off >>= 1) x += __shfl_down(x, off, 64);
    if (d == 0) {
        float z = x + b_disc[0];
        out[w] = 1.f / (1.f + expf(-z));
    }
}

__global__ void impact_kernel(const int* __restrict__ eid, const float* __restrict__ imp,
                              float* out) {
    int i = blockIdx.x * 256 + threadIdx.x;
    if (i >= B_N * 64) return;
    int b = i >> 6, d = i & 63;
    out[i] = imp[(long)eid[b] * 64 + d];
}

// --------------------------------------------- big GEMM: [B,128] @ [128,1024p]^T
// wave computes 32x32 (2x2 tiles of mfma_f32_16x16x32_bf16), block = 4 waves = 64x64
__global__ void big_mm(const __hip_bfloat16* __restrict__ st, const __hip_bfloat16* __restrict__ df,
                       const __hip_bfloat16* __restrict__ kn,
                       float* __restrict__ out0, float* __restrict__ out1) {
    const ushort* X = (const ushort*)(blockIdx.z ? df : st);
    const ushort* Kn = (const ushort*)kn;
    float* out = blockIdx.z ? out1 : out0;
    int wv = threadIdx.x >> 6;
    int lane = threadIdx.x & 63;
    int m_blk = blockIdx.y * 64 + (wv >> 1) * 32;
    int n_blk = blockIdx.x * 64 + (wv & 1) * 32;
    int q = lane >> 4, l16 = lane & 15;
    f4 acc00 = {0.f, 0.f, 0.f, 0.f}, acc01 = acc00, acc10 = acc00, acc11 = acc00;
    for (int s = 0; s < 4; s++) {
        int kofs = s * 32 + q * 8;
        sh8 a0 = *(const sh8*)&X[(long)(m_blk + l16) * 128 + kofs];
        sh8 a1 = *(const sh8*)&X[(long)(m_blk + 16 + l16) * 128 + kofs];
        sh8 b0 = *(const sh8*)&Kn[(long)(n_blk + l16) * 128 + kofs];
        sh8 b1 = *(const sh8*)&Kn[(long)(n_blk + 16 + l16) * 128 + kofs];
        acc00 = __builtin_amdgcn_mfma_f32_16x16x32_bf16(a0, b0, acc00, 0, 0, 0);
        acc01 = __builtin_amdgcn_mfma_f32_16x16x32_bf16(a0, b1, acc01, 0, 0, 0);
        acc10 = __builtin_amdgcn_mfma_f32_16x16x32_bf16(a1, b0, acc10, 0, 0, 0);
        acc11 = __builtin_amdgcn_mfma_f32_16x16x32_bf16(a1, b1, acc11, 0, 0, 0);
    }
    // C/D layout: col = lane&15, row = (lane>>4)*4 + reg
    for (int r = 0; r < 4; r++) {
        int row0 = m_blk + q * 4 + r;
        int row1 = m_blk + 16 + q * 4 + r;
        int col0 = n_blk + l16;
        int col1 = n_blk + 16 + l16;
        if (col0 < K_N) {
            out[(long)row0 * K_N + col0] = acc00[r];
            out[(long)row1 * K_N + col0] = acc10[r];
        }
        if (col1 < K_N) {
            out[(long)row0 * K_N + col1] = acc01[r];
            out[(long)row1 * K_N + col1] = acc11[r];
        }
    }
}

// ---------------------------------------------------------------------------
extern "C" void kernel_launch(void* const* d_in, const int* in_sizes, int n_in,
                              void* d_out, int out_size, void* d_ws, size_t ws_size,
                              hipStream_t stream) {
    const int* sid = (const int*)d_in[0];
    const int* eid = (const int*)d_in[1];
    // d_in[2] q_mask unused
    const float* stu_emb = (const float*)d_in[3];
    const float* exer_emb = (const float*)d_in[4];
    const float* know_emb = (const float*)d_in[5];
    const float* impact_emb = (const float*)d_in[6];
    const int* s_rows = (const int*)d_in[7];
    const int* s_cols = (const int*)d_in[8];
    const float* s_vals = (const float*)d_in[9];
    const int* e_rows = (const int*)d_in[10];
    const int* e_cols = (const int*)d_in[11];
    const float* e_vals = (const float*)d_in[12];
    const int* k_rows = (const int*)d_in[13];
    const int* k_cols = (const int*)d_in[14];
    const float* k_vals = (const float*)d_in[15];
    const float* W_stu = (const float*)d_in[16];
    const float* b_stu = (const float*)d_in[17];
    const float* W_exer = (const float*)d_in[18];
    const float* b_exer = (const float*)d_in[19];
    const float* W_know = (const float*)d_in[20];
    const float* b_know = (const float*)d_in[21];
    const float* W_disc = (const float*)d_in[22];
    const float* b_disc = (const float*)d_in[23];

    float* out = (float*)d_out;
    float* out_st = out;                       // [B,1000]
    float* out_df = out + 16384000;            // [B,1000]
    float* out_disc = out + 32768000;          // [B,1]
    float* out_kn = out + 32784384;            // [1000,128]
    float* out_imp = out + 32912384;           // [B,64]

    char* p = (char*)d_ws;
    auto alloc = [&](size_t bytes) -> char* {
        char* r = p;
        p += (bytes + 255) & ~(size_t)255;
        return r;
    };
    float* bufA_s = (float*)alloc((size_t)S_N * 64 * 4);
    float* bufB_s = (float*)alloc((size_t)S_N * 64 * 4);
    float* bufA_e = (float*)alloc((size_t)E_N * 64 * 4);
    float* bufB_e = (float*)alloc((size_t)E_N * 64 * 4);
    float* bufA_k = (float*)alloc((size_t)K_N * 64 * 4);
    float* bufB_k = (float*)alloc((size_t)K_N * 64 * 4);
    float* bacc_s = (float*)alloc((size_t)B_N * 64 * 4);
    float* bacc_e = (float*)alloc((size_t)B_N * 64 * 4);
    float* kacc = (float*)alloc((size_t)K_N * 64 * 4);
    __hip_bfloat16* st_b = (__hip_bfloat16*)alloc((size_t)B_N * 128 * 2);
    __hip_bfloat16* df_b = (__hip_bfloat16*)alloc((size_t)B_N * 128 * 2);
    __hip_bfloat16* kn_b = (__hip_bfloat16*)alloc((size_t)1024 * 128 * 2);
    int* cnt_s = (int*)alloc((size_t)(S_N + E_N + K_N) * 4);  // contiguous for one memset
    int* cnt_e = cnt_s + S_N;
    int* cnt_k = cnt_e + E_N;
    int* rp_s = (int*)alloc((size_t)(S_N + 1) * 4);
    int* rp_e = (int*)alloc((size_t)(E_N + 1) * 4);
    int* rp_k = (int*)alloc((size_t)(K_N + 1) * 4);
    int* nx_s = (int*)alloc((size_t)S_N * 4);
    int* nx_e = (int*)alloc((size_t)E_N * 4);
    int* nx_k = (int*)alloc((size_t)K_N * 4);
    int* cs_s = (int*)alloc((size_t)NNZ_S * 4);
    float* vs_s = (float*)alloc((size_t)NNZ_S * 4);
    int* cs_e = (int*)alloc((size_t)NNZ_E * 4);
    float* vs_e = (float*)alloc((size_t)NNZ_E * 4);
    int* cs_k = (int*)alloc((size_t)NNZ_K * 4);
    float* vs_k = (float*)alloc((size_t)NNZ_K * 4);
    int* partials = (int*)alloc(CH_TOT * 4);
    int* chunk_off = (int*)alloc(CH_TOT * 4);

    // ---- CSR build
    hipMemsetAsync(cnt_s, 0, (size_t)(S_N + E_N + K_N) * 4, stream);
    count_kernel<<<NNZ_TOT / 256, 256, 0, stream>>>(s_rows, e_rows, k_rows, cnt_s, cnt_e, cnt_k);
    scan_a<<<CH_TOT, 256, 0, stream>>>(cnt_s, cnt_e, cnt_k, partials);
    scan_b<<<1, 64, 0, stream>>>(partials, chunk_off, rp_s, rp_e, rp_k);
    scan_c<<<CH_TOT, 256, 0, stream>>>(cnt_s, cnt_e, cnt_k, chunk_off,
                                       rp_s, rp_e, rp_k, nx_s, nx_e, nx_k);
    scatter_kernel<<<NNZ_TOT / 256, 256, 0, stream>>>(
        s_rows, s_cols, s_vals, e_rows, e_cols, e_vals, k_rows, k_cols, k_vals,
        nx_s, nx_e, nx_k, cs_s, vs_s, cs_e, vs_e, cs_k, vs_k);

    // ---- convolution: G1(emb), L1, G2(cur1), L2, G3(cur2), L3
    const int gather_blocks = (2 * B_N * 64 + K_N * 64) / 256;
    const int spmm_blocks = (S_N + E_N + K_N + 3) / 4;
    gather_acc<<<gather_blocks, 256, 0, stream>>>(sid, eid, stu_emb, exer_emb, know_emb,
                                                  bacc_s, bacc_e, kacc, 1);
    spmm3<<<spmm_blocks, 256, 0, stream>>>(rp_s, cs_s, vs_s, stu_emb, bufA_s,
                                           rp_e, cs_e, vs_e, exer_emb, bufA_e,
                                           rp_k, cs_k, vs_k, know_emb, bufA_k);
    gather_acc<<<gather_blocks, 256, 0, stream>>>(sid, eid, bufA_s, bufA_e, bufA_k,
                                                  bacc_s, bacc_e, kacc, 0);
    spmm3<<<spmm_blocks, 256, 0, stream>>>(rp_s, cs_s, vs_s, bufA_s, bufB_s,
                                           rp_e, cs_e, vs_e, bufA_e, bufB_e,
                                           rp_k, cs_k, vs_k, bufA_k, bufB_k);
    gather_acc<<<gather_blocks, 256, 0, stream>>>(sid, eid, bufB_s, bufB_e, bufB_k,
                                                  bacc_s, bacc_e, kacc, 0);
    spmm3<<<spmm_blocks, 256, 0, stream>>>(rp_s, cs_s, vs_s, bufB_s, bufA_s,
                                           rp_e, cs_e, vs_e, bufB_e, bufA_e,
                                           rp_k, cs_k, vs_k, bufB_k, bufA_k);
    // cur3 now in bufA_*; dense stage folds the last gather and the /4 scale

    // ---- dense stage
    dense_mm<<<dim3(B_N / 2, 2), 256, 0, stream>>>(sid, eid, bacc_s, bufA_s, bacc_e, bufA_e,
                                                   W_stu, b_stu, W_exer, b_exer, st_b, df_b);
    know_mm<<<512, 256, 0, stream>>>(kacc, bufA_k, W_know, b_know, out_kn, kn_b);
    disc_kernel<<<B_N / 4, 256, 0, stream>>>(eid, bacc_e, bufA_e, W_disc, b_disc, out_disc);
    impact_kernel<<<B_N * 64 / 256, 256, 0, stream>>>(eid, impact_emb, out_imp);

    // ---- big GEMMs: [B,128] @ kn^T -> [B,1000], both in one kernel (z = 0/1)
    big_mm<<<dim3(16, B_N / 64, 2), 256, 0, stream>>>(st_b, df_b, kn_b, out_st, out_df);
}

// Round 2
// 870.556 us; speedup vs baseline: 1.3301x; 1.3301x over previous
//
#include <hip/hip_runtime.h>
#include <hip/hip_bf16.h>

#define S_N 100000
#define E_N 30000
#define K_N 1000
#define D_K 64
#define F_K 128
#define B_N 16384
#define NNZ_S 1600000
#define NNZ_E 480000
#define NNZ_K 32000
#define NNZ_TOT (NNZ_S + NNZ_E + NNZ_K)

// scan chunking: 2048 elements per block (256 threads x 8)
#define CH_S 49   // ceil(100000/2048)
#define CH_E 15   // ceil(30000/2048)
#define CH_K 1
#define CH_TOT (CH_S + CH_E + CH_K)

typedef __attribute__((ext_vector_type(8))) short sh8;
typedef __attribute__((ext_vector_type(4))) float f4;

__device__ inline float b2f(ushort u) { return __uint_as_float((unsigned)u << 16); }
__device__ inline ushort f2b(float f) {
    unsigned u = __float_as_uint(f);
    return (ushort)((u + 0x7fffu + ((u >> 16) & 1u)) >> 16);
}

// ---------------------------------------------------------------- CSR build
__global__ void count_kernel(const int* __restrict__ sr, const int* __restrict__ er,
                             const int* __restrict__ kr,
                             int* cnt_s, int* cnt_e, int* cnt_k) {
    int i = blockIdx.x * 256 + threadIdx.x;
    if (i >= NNZ_TOT) return;
    if (i < NNZ_S) atomicAdd(&cnt_s[sr[i]], 1);
    else if (i < NNZ_S + NNZ_E) atomicAdd(&cnt_e[er[i - NNZ_S]], 1);
    else atomicAdd(&cnt_k[kr[i - NNZ_S - NNZ_E]], 1);
}

__device__ inline void seg_map(int b, const int* cnt_s, const int* cnt_e, const int* cnt_k,
                               const int** src, int* len, int* chunk, int* seg) {
    if (b < CH_S)            { *src = cnt_s; *len = S_N; *chunk = b;            *seg = 0; }
    else if (b < CH_S + CH_E){ *src = cnt_e; *len = E_N; *chunk = b - CH_S;     *seg = 1; }
    else                     { *src = cnt_k; *len = K_N; *chunk = 0;            *seg = 2; }
}

__global__ void scan_a(const int* cnt_s, const int* cnt_e, const int* cnt_k, int* partials) {
    const int* src; int len, chunk, seg;
    seg_map(blockIdx.x, cnt_s, cnt_e, cnt_k, &src, &len, &chunk, &seg);
    int base = chunk * 2048 + threadIdx.x * 8;
    int s = 0;
    for (int j = 0; j < 8; j++) { int idx = base + j; if (idx < len) s += src[idx]; }
    __shared__ int red[256];
    red[threadIdx.x] = s; __syncthreads();
    for (int off = 128; off > 0; off >>= 1) {
        if (threadIdx.x < off) red[threadIdx.x] += red[threadIdx.x + off];
        __syncthreads();
    }
    if (threadIdx.x == 0) partials[blockIdx.x] = red[0];
}

__global__ void scan_b(const int* partials, int* chunk_off, int* rp_s, int* rp_e, int* rp_k) {
    if (threadIdx.x == 0 && blockIdx.x == 0) {
        int acc = 0;
        for (int i = 0; i < CH_S; i++) { chunk_off[i] = acc; acc += partials[i]; }
        rp_s[S_N] = acc;
        acc = 0;
        for (int i = CH_S; i < CH_S + CH_E; i++) { chunk_off[i] = acc; acc += partials[i]; }
        rp_e[E_N] = acc;
        chunk_off[CH_S + CH_E] = 0;
        rp_k[K_N] = partials[CH_S + CH_E];
    }
}

__global__ void scan_c(const int* cnt_s, const int* cnt_e, const int* cnt_k,
                       const int* chunk_off,
                       int* rp_s, int* rp_e, int* rp_k,
                       int* nx_s, int* nx_e, int* nx_k) {
    const int* src; int len, chunk, seg;
    seg_map(blockIdx.x, cnt_s, cnt_e, cnt_k, &src, &len, &chunk, &seg);
    int* rp = (seg == 0) ? rp_s : (seg == 1) ? rp_e : rp_k;
    int* nx = (seg == 0) ? nx_s : (seg == 1) ? nx_e : nx_k;
    int t = threadIdx.x;
    int base = chunk * 2048 + t * 8;
    int v[8]; int s = 0;
    for (int j = 0; j < 8; j++) { int idx = base + j; v[j] = (idx < len) ? src[idx] : 0; s += v[j]; }
    __shared__ int sd[256];
    sd[t] = s; __syncthreads();
    for (int off = 1; off < 256; off <<= 1) {
        int x = (t >= off) ? sd[t - off] : 0;
        __syncthreads();
        sd[t] += x;
        __syncthreads();
    }
    int pre = sd[t] - s + chunk_off[blockIdx.x];
    for (int j = 0; j < 8; j++) {
        int idx = base + j;
        if (idx < len) { rp[idx] = pre; nx[idx] = pre; pre += v[j]; }
    }
}

// scatter (col, val) interleaved as int2 -> one 8B store per nnz
__global__ void scatter_kernel(const int* sr, const int* sc, const float* sv,
                               const int* er, const int* ec, const float* ev,
                               const int* kr, const int* kc, const float* kv,
                               int* nx_s, int* nx_e, int* nx_k,
                               int2* pr_s, int2* pr_e, int2* pr_k) {
    int i = blockIdx.x * 256 + threadIdx.x;
    if (i >= NNZ_TOT) return;
    if (i < NNZ_S) {
        int r = sr[i]; int p = atomicAdd(&nx_s[r], 1);
        pr_s[p] = make_int2(sc[i], __float_as_int(sv[i]));
    } else if (i < NNZ_S + NNZ_E) {
        int ii = i - NNZ_S;
        int r = er[ii]; int p = atomicAdd(&nx_e[r], 1);
        pr_e[p] = make_int2(ec[ii], __float_as_int(ev[ii]));
    } else {
        int ii = i - NNZ_S - NNZ_E;
        int r = kr[ii]; int p = atomicAdd(&nx_k[r], 1);
        pr_k[p] = make_int2(kc[ii], __float_as_int(kv[ii]));
    }
}

// ------------------------------------------------ f32 -> bf16 convert (embs)
__global__ void convert_bf16(const float* __restrict__ a, const float* __restrict__ b,
                             const float* __restrict__ c,
                             ushort* oa, ushort* ob, ushort* oc) {
    const int NA = S_N * 64, NB = E_N * 64, NC = K_N * 64;
    int i = (blockIdx.x * 256 + threadIdx.x) * 4;
    const float* src; ushort* dst; int n;
    if (i < NA) { src = a; dst = oa; n = NA; }
    else if (i < NA + NB) { i -= NA; src = b; dst = ob; n = NB; }
    else if (i < NA + NB + NC) { i -= NA + NB; src = c; dst = oc; n = NC; }
    else return;
    float4 v = *(const float4*)&src[i];
    ushort4 o;
    o.x = f2b(v.x); o.y = f2b(v.y); o.z = f2b(v.z); o.w = f2b(v.w);
    *(ushort4*)&dst[i] = o;
}

// --------------------------------------------------------- convolution SpMM
// one wave per row, lane = feature d; y[r] = 0.9*x[r] + sum val*x[col]
// bf16 x/y, f32 accumulate, nnz loop unrolled x4 for memory-level parallelism
__global__ void spmm3(const int* __restrict__ rp_s, const int2* __restrict__ pr_s,
                      const ushort* __restrict__ xs, ushort* ys,
                      const int* __restrict__ rp_e, const int2* __restrict__ pr_e,
                      const ushort* __restrict__ xe, ushort* ye,
                      const int* __restrict__ rp_k, const int2* __restrict__ pr_k,
                      const ushort* __restrict__ xk, ushort* yk) {
    int w = (blockIdx.x * 256 + threadIdx.x) >> 6;
    int d = threadIdx.x & 63;
    const int* rp; const int2* pr; const ushort* x; ushort* y; int r;
    if (w < S_N) { rp = rp_s; pr = pr_s; x = xs; y = ys; r = w; }
    else if (w < S_N + E_N) { rp = rp_e; pr = pr_e; x = xe; y = ye; r = w - S_N; }
    else if (w < S_N + E_N + K_N) { rp = rp_k; pr = pr_k; x = xk; y = yk; r = w - S_N - E_N; }
    else return;
    int j0 = rp[r], j1 = rp[r + 1];
    float acc = 0.9f * b2f(x[(long)r * 64 + d]);
    int j = j0;
    for (; j + 4 <= j1; j += 4) {
        int2 p0 = pr[j], p1 = pr[j + 1], p2 = pr[j + 2], p3 = pr[j + 3];
        float x0 = b2f(x[(long)p0.x * 64 + d]);
        float x1 = b2f(x[(long)p1.x * 64 + d]);
        float x2 = b2f(x[(long)p2.x * 64 + d]);
        float x3 = b2f(x[(long)p3.x * 64 + d]);
        acc = fmaf(__int_as_float(p0.y), x0, acc);
        acc = fmaf(__int_as_float(p1.y), x1, acc);
        acc = fmaf(__int_as_float(p2.y), x2, acc);
        acc = fmaf(__int_as_float(p3.y), x3, acc);
    }
    for (; j < j1; j++) {
        int2 p = pr[j];
        acc = fmaf(__int_as_float(p.y), b2f(x[(long)p.x * 64 + d]), acc);
    }
    y[(long)r * 64 + d] = f2b(acc);
}

// ------------------------------------------------- batch accumulator gathers
// layer-0 init from f32 embeddings
__global__ void gather_init(const int* __restrict__ sid, const int* __restrict__ eid,
                            const float* __restrict__ src_s, const float* __restrict__ src_e,
                            const float* __restrict__ src_k,
                            float* bacc_s, float* bacc_e, float* kacc) {
    int i = blockIdx.x * 256 + threadIdx.x;
    const int BD = B_N * 64;
    if (i < BD) {
        int b = i >> 6, d = i & 63;
        bacc_s[i] = src_s[(long)sid[b] * 64 + d];
    } else if (i < 2 * BD) {
        int ii = i - BD; int b = ii >> 6, d = ii & 63;
        bacc_e[ii] = src_e[(long)eid[b] * 64 + d];
    } else if (i < 2 * BD + K_N * 64) {
        int ii = i - 2 * BD;
        kacc[ii] = src_k[ii];
    }
}

// layers 1..3 accumulate from bf16 conv outputs
__global__ void gather_accb(const int* __restrict__ sid, const int* __restrict__ eid,
                            const ushort* __restrict__ src_s, const ushort* __restrict__ src_e,
                            const ushort* __restrict__ src_k,
                            float* bacc_s, float* bacc_e, float* kacc) {
    int i = blockIdx.x * 256 + threadIdx.x;
    const int BD = B_N * 64;
    if (i < BD) {
        int b = i >> 6, d = i & 63;
        bacc_s[i] += b2f(src_s[(long)sid[b] * 64 + d]);
    } else if (i < 2 * BD) {
        int ii = i - BD; int b = ii >> 6, d = ii & 63;
        bacc_e[ii] += b2f(src_e[(long)eid[b] * 64 + d]);
    } else if (i < 2 * BD + K_N * 64) {
        int ii = i - 2 * BD;
        kacc[ii] += b2f(src_k[ii]);
    }
}

// --------------------------------------------- small dense layers (D=64 -> F=128)
// block: 2 rows x 128 cols; X = 0.25*(bacc + cur3[id]); out = leaky(X@W + b) in bf16
__global__ void dense_mm(const int* __restrict__ sid, const int* __restrict__ eid,
                         const float* __restrict__ bacc_s, const ushort* __restrict__ cur3_s,
                         const float* __restrict__ bacc_e, const ushort* __restrict__ cur3_e,
                         const float* __restrict__ W_stu, const float* __restrict__ b_stu,
                         const float* __restrict__ W_exer, const float* __restrict__ b_exer,
                         __hip_bfloat16* st_b, __hip_bfloat16* df_b) {
    int which = blockIdx.y;
    const int* id = which ? eid : sid;
    const float* bacc = which ? bacc_e : bacc_s;
    const ushort* cur3 = which ? cur3_e : cur3_s;
    const float* W = which ? W_exer : W_stu;
    const float* bias = which ? b_exer : b_stu;
    __hip_bfloat16* out = which ? df_b : st_b;
    int r0 = blockIdx.x * 2;
    int t = threadIdx.x;
    __shared__ float X[2][64];
    if (t < 128) {
        int lr = t >> 6, d = t & 63; int b = r0 + lr;
        X[lr][d] = 0.25f * (bacc[(long)b * 64 + d] + b2f(cur3[(long)id[b] * 64 + d]));
    }
    __syncthreads();
    int lr = t >> 7, f = t & 127;
    float acc = bias[f];
    for (int d = 0; d < 64; d++) acc += X[lr][d] * W[d * 128 + f];
    acc = acc > 0.f ? acc : 0.1f * acc;
    out[(long)(r0 + lr) * 128 + f] = __float2bfloat16(acc);
}

// knowledge: rows padded to 1024; writes f32 to d_out and bf16 (zero-padded) to ws
__global__ void know_mm(const float* __restrict__ kacc, const ushort* __restrict__ cur3_k,
                        const float* __restrict__ W, const float* __restrict__ bias,
                        float* out_f32, __hip_bfloat16* kn_b) {
    int r0 = blockIdx.x * 2;
    int t = threadIdx.x;
    __shared__ float X[2][64];
    if (t < 128) {
        int lr = t >> 6, d = t & 63; int r = r0 + lr;
        X[lr][d] = (r < K_N) ? 0.25f * (kacc[r * 64 + d] + b2f(cur3_k[r * 64 + d])) : 0.f;
    }
    __syncthreads();
    int lr = t >> 7, f = t & 127; int r = r0 + lr;
    float acc = bias[f];
    for (int d = 0; d < 64; d++) acc += X[lr][d] * W[d * 128 + f];
    acc = acc > 0.f ? acc : 0.1f * acc;
    if (r < K_N) {
        out_f32[(long)r * 128 + f] = acc;
        kn_b[(long)r * 128 + f] = __float2bfloat16(acc);
    } else {
        kn_b[(long)r * 128 + f] = __float2bfloat16(0.f);
    }
}

// disc = sigmoid(0.25*(bacc_e+cur3_e[eid]) . W_disc + b_disc), one wave per row
__global__ void disc_kernel(const int* __restrict__ eid,
                            const float* __restrict__ bacc_e, const ushort* __restrict__ cur3_e,
                            const float* __restrict__ W_disc, const float* __restrict__ b_disc,
                            float* out) {
    int w = (blockIdx.x * 256 + threadIdx.x) >> 6;
    int d = threadIdx.x & 63;
    if (w >= B_N) return;
    float x = 0.25f * (bacc_e[(long)w * 64 + d] + b2f(cur3_e[(long)eid[w] * 64 + d])) * W_disc[d];
    for (int off = 32; off > 0; off >>= 1) x += __shfl_down(x, off, 64);
    if (d == 0) {
        float z = x + b_disc[0];
        out[w] = 1.f / (1.f + expf(-z));
    }
}

__global__ void impact_kernel(const int* __restrict__ eid, const float* __restrict__ imp,
                              float* out) {
    int i = blockIdx.x * 256 + threadIdx.x;
    if (i >= B_N * 64) return;
    int b = i >> 6, d = i & 63;
    out[i] = imp[(long)eid[b] * 64 + d];
}

// --------------------------------------------- big GEMM: [B,128] @ [128,1024p]^T
// wave computes 32x32 (2x2 tiles of mfma_f32_16x16x32_bf16), block = 4 waves = 64x64
__global__ void big_mm(const __hip_bfloat16* __restrict__ st, const __hip_bfloat16* __restrict__ df,
                       const __hip_bfloat16* __restrict__ kn,
                       float* __restrict__ out0, float* __restrict__ out1) {
    const ushort* X = (const ushort*)(blockIdx.z ? df : st);
    const ushort* Kn = (const ushort*)kn;
    float* out = blockIdx.z ? out1 : out0;
    int wv = threadIdx.x >> 6;
    int lane = threadIdx.x & 63;
    int m_blk = blockIdx.y * 64 + (wv >> 1) * 32;
    int n_blk = blockIdx.x * 64 + (wv & 1) * 32;
    int q = lane >> 4, l16 = lane & 15;
    f4 acc00 = {0.f, 0.f, 0.f, 0.f}, acc01 = acc00, acc10 = acc00, acc11 = acc00;
    for (int s = 0; s < 4; s++) {
        int kofs = s * 32 + q * 8;
        sh8 a0 = *(const sh8*)&X[(long)(m_blk + l16) * 128 + kofs];
        sh8 a1 = *(const sh8*)&X[(long)(m_blk + 16 + l16) * 128 + kofs];
        sh8 b0 = *(const sh8*)&Kn[(long)(n_blk + l16) * 128 + kofs];
        sh8 b1 = *(const sh8*)&Kn[(long)(n_blk + 16 + l16) * 128 + kofs];
        acc00 = __builtin_amdgcn_mfma_f32_16x16x32_bf16(a0, b0, acc00, 0, 0, 0);
        acc01 = __builtin_amdgcn_mfma_f32_16x16x32_bf16(a0, b1, acc01, 0, 0, 0);
        acc10 = __builtin_amdgcn_mfma_f32_16x16x32_bf16(a1, b0, acc10, 0, 0, 0);
        acc11 = __builtin_amdgcn_mfma_f32_16x16x32_bf16(a1, b1, acc11, 0, 0, 0);
    }
    // C/D layout: col = lane&15, row = (lane>>4)*4 + reg
    for (int r = 0; r < 4; r++) {
        int row0 = m_blk + q * 4 + r;
        int row1 = m_blk + 16 + q * 4 + r;
        int col0 = n_blk + l16;
        int col1 = n_blk + 16 + l16;
        if (col0 < K_N) {
            out[(long)row0 * K_N + col0] = acc00[r];
            out[(long)row1 * K_N + col0] = acc10[r];
        }
        if (col1 < K_N) {
            out[(long)row0 * K_N + col1] = acc01[r];
            out[(long)row1 * K_N + col1] = acc11[r];
        }
    }
}

// ---------------------------------------------------------------------------
extern "C" void kernel_launch(void* const* d_in, const int* in_sizes, int n_in,
                              void* d_out, int out_size, void* d_ws, size_t ws_size,
                              hipStream_t stream) {
    const int* sid = (const int*)d_in[0];
    const int* eid = (const int*)d_in[1];
    // d_in[2] q_mask unused
    const float* stu_emb = (const float*)d_in[3];
    const float* exer_emb = (const float*)d_in[4];
    const float* know_emb = (const float*)d_in[5];
    const float* impact_emb = (const float*)d_in[6];
    const int* s_rows = (const int*)d_in[7];
    const int* s_cols = (const int*)d_in[8];
    const float* s_vals = (const float*)d_in[9];
    const int* e_rows = (const int*)d_in[10];
    const int* e_cols = (const int*)d_in[11];
    const float* e_vals = (const float*)d_in[12];
    const int* k_rows = (const int*)d_in[13];
    const int* k_cols = (const int*)d_in[14];
    const float* k_vals = (const float*)d_in[15];
    const float* W_stu = (const float*)d_in[16];
    const float* b_stu = (const float*)d_in[17];
    const float* W_exer = (const float*)d_in[18];
    const float* b_exer = (const float*)d_in[19];
    const float* W_know = (const float*)d_in[20];
    const float* b_know = (const float*)d_in[21];
    const float* W_disc = (const float*)d_in[22];
    const float* b_disc = (const float*)d_in[23];

    float* out = (float*)d_out;
    float* out_st = out;                       // [B,1000]
    float* out_df = out + 16384000;            // [B,1000]
    float* out_disc = out + 32768000;          // [B,1]
    float* out_kn = out + 32784384;            // [1000,128]
    float* out_imp = out + 32912384;           // [B,64]

    char* p = (char*)d_ws;
    auto alloc = [&](size_t bytes) -> char* {
        char* r = p;
        p += (bytes + 255) & ~(size_t)255;
        return r;
    };
    ushort* xb_s = (ushort*)alloc((size_t)S_N * 64 * 2);   // bf16 embeddings
    ushort* xb_e = (ushort*)alloc((size_t)E_N * 64 * 2);
    ushort* xb_k = (ushort*)alloc((size_t)K_N * 64 * 2);
    ushort* bufA_s = (ushort*)alloc((size_t)S_N * 64 * 2);
    ushort* bufB_s = (ushort*)alloc((size_t)S_N * 64 * 2);
    ushort* bufA_e = (ushort*)alloc((size_t)E_N * 64 * 2);
    ushort* bufB_e = (ushort*)alloc((size_t)E_N * 64 * 2);
    ushort* bufA_k = (ushort*)alloc((size_t)K_N * 64 * 2);
    ushort* bufB_k = (ushort*)alloc((size_t)K_N * 64 * 2);
    float* bacc_s = (float*)alloc((size_t)B_N * 64 * 4);
    float* bacc_e = (float*)alloc((size_t)B_N * 64 * 4);
    float* kacc = (float*)alloc((size_t)K_N * 64 * 4);
    __hip_bfloat16* st_b = (__hip_bfloat16*)alloc((size_t)B_N * 128 * 2);
    __hip_bfloat16* df_b = (__hip_bfloat16*)alloc((size_t)B_N * 128 * 2);
    __hip_bfloat16* kn_b = (__hip_bfloat16*)alloc((size_t)1024 * 128 * 2);
    int* cnt_s = (int*)alloc((size_t)(S_N + E_N + K_N) * 4);  // contiguous for one memset
    int* cnt_e = cnt_s + S_N;
    int* cnt_k = cnt_e + E_N;
    int* rp_s = (int*)alloc((size_t)(S_N + 1) * 4);
    int* rp_e = (int*)alloc((size_t)(E_N + 1) * 4);
    int* rp_k = (int*)alloc((size_t)(K_N + 1) * 4);
    int* nx_s = (int*)alloc((size_t)S_N * 4);
    int* nx_e = (int*)alloc((size_t)E_N * 4);
    int* nx_k = (int*)alloc((size_t)K_N * 4);
    int2* pr_s = (int2*)alloc((size_t)NNZ_S * 8);
    int2* pr_e = (int2*)alloc((size_t)NNZ_E * 8);
    int2* pr_k = (int2*)alloc((size_t)NNZ_K * 8);
    int* partials = (int*)alloc(CH_TOT * 4);
    int* chunk_off = (int*)alloc(CH_TOT * 4);

    // ---- CSR build
    hipMemsetAsync(cnt_s, 0, (size_t)(S_N + E_N + K_N) * 4, stream);
    count_kernel<<<NNZ_TOT / 256, 256, 0, stream>>>(s_rows, e_rows, k_rows, cnt_s, cnt_e, cnt_k);
    scan_a<<<CH_TOT, 256, 0, stream>>>(cnt_s, cnt_e, cnt_k, partials);
    scan_b<<<1, 64, 0, stream>>>(partials, chunk_off, rp_s, rp_e, rp_k);
    scan_c<<<CH_TOT, 256, 0, stream>>>(cnt_s, cnt_e, cnt_k, chunk_off,
                                       rp_s, rp_e, rp_k, nx_s, nx_e, nx_k);
    scatter_kernel<<<NNZ_TOT / 256, 256, 0, stream>>>(
        s_rows, s_cols, s_vals, e_rows, e_cols, e_vals, k_rows, k_cols, k_vals,
        nx_s, nx_e, nx_k, pr_s, pr_e, pr_k);

    // ---- bf16 convert of embeddings (spmm inputs)
    const int conv_blocks = ((S_N + E_N + K_N) * 64 / 4 + 255) / 256;
    convert_bf16<<<conv_blocks, 256, 0, stream>>>(stu_emb, exer_emb, know_emb, xb_s, xb_e, xb_k);

    // ---- convolution: G1(emb f32), L1, G2(cur1), L2, G3(cur2), L3
    const int gather_blocks = (2 * B_N * 64 + K_N * 64) / 256;
    const int spmm_blocks = (S_N + E_N + K_N + 3) / 4;
    gather_init<<<gather_blocks, 256, 0, stream>>>(sid, eid, stu_emb, exer_emb, know_emb,
                                                   bacc_s, bacc_e, kacc);
    spmm3<<<spmm_blocks, 256, 0, stream>>>(rp_s, pr_s, xb_s, bufA_s,
                                           rp_e, pr_e, xb_e, bufA_e,
                                           rp_k, pr_k, xb_k, bufA_k);
    gather_accb<<<gather_blocks, 256, 0, stream>>>(sid, eid, bufA_s, bufA_e, bufA_k,
                                                   bacc_s, bacc_e, kacc);
    spmm3<<<spmm_blocks, 256, 0, stream>>>(rp_s, pr_s, bufA_s, bufB_s,
                                           rp_e, pr_e, bufA_e, bufB_e,
                                           rp_k, pr_k, bufA_k, bufB_k);
    gather_accb<<<gather_blocks, 256, 0, stream>>>(sid, eid, bufB_s, bufB_e, bufB_k,
                                                   bacc_s, bacc_e, kacc);
    spmm3<<<spmm_blocks, 256, 0, stream>>>(rp_s, pr_s, bufB_s, bufA_s,
                                           rp_e, pr_e, bufB_e, bufA_e,
                                           rp_k, pr_k, bufB_k, bufA_k);
    // cur3 now in bufA_* (bf16); dense stage folds the last gather and the /4 scale

    // ---- dense stage
    dense_mm<<<dim3(B_N / 2, 2), 256, 0, stream>>>(sid, eid, bacc_s, bufA_s, bacc_e, bufA_e,
                                                   W_stu, b_stu, W_exer, b_exer, st_b, df_b);
    know_mm<<<512, 256, 0, stream>>>(kacc, bufA_k, W_know, b_know, out_kn, kn_b);
    disc_kernel<<<B_N / 4, 256, 0, stream>>>(eid, bacc_e, bufA_e, W_disc, b_disc, out_disc);
    impact_kernel<<<B_N * 64 / 256, 256, 0, stream>>>(eid, impact_emb, out_imp);

    // ---- big GEMMs: [B,128] @ kn^T -> [B,1000], both in one kernel (z = 0/1)
    big_mm<<<dim3(16, B_N / 64, 2), 256, 0, stream>>>(st_b, df_b, kn_b, out_st, out_df);
}